// Round 11
// baseline (270.232 us; speedup 1.0000x reference)
//
#include <hip/hip_runtime.h>

// ---------------------------------------------------------------------------
// GCN 3-layer forward. Round 11: occupancy/latency cleanup off the gather
// critical path (gather128 is ~15% above its structural floor: 8 XCDs x
// 25.6MB table / non-coherent 4MB L2s => ~190-205MB L3 fetch @ ~3.6TB/s):
//   - csrbuild: 512 threads/block (8 waves; was 4) to hide 2-pass latency
//   - gemm: 512 threads / 128 rows per block (halves W-staging overhead)
//   - gather64: 8-deep edge unroll (was 4)
// ---------------------------------------------------------------------------

typedef __attribute__((ext_vector_type(8))) short short8;
typedef __attribute__((ext_vector_type(4))) float f32x4;
typedef __attribute__((ext_vector_type(4))) int i32x4;
typedef __attribute__((ext_vector_type(4))) float fp32x4;

__device__ __forceinline__ unsigned short f2bf(float f) {
  union { float f; unsigned u; } v; v.f = f;
  unsigned r = v.u + 0x7fffu + ((v.u >> 16) & 1u);  // RNE
  return (unsigned short)(r >> 16);
}
__device__ __forceinline__ float bf2f(unsigned short h) {
  union { unsigned u; float f; } v; v.u = (unsigned)h << 16;
  return v.f;
}

constexpr int ABLK = 512;      // blocks in binning passes (2 blocks/CU)
constexpr int BINSHIFT = 8;    // 256 nodes per bin
constexpr int MAXBINS = 512;
constexpr int SRCBITS = 17;    // N < 131072
constexpr int SRCMASK = (1 << SRCBITS) - 1;

// ---- pass A1: G[bin*ABLK + blk] = count of this block's edges in bin ----
__global__ __launch_bounds__(256) void binhist_kernel(
    const int* __restrict__ dst, int* __restrict__ G, int E, int nbins,
    int chunk) {
  __shared__ int h[MAXBINS];
  for (int i = threadIdx.x; i < nbins; i += 256) h[i] = 0;
  __syncthreads();
  const int base = blockIdx.x * chunk;
  const int end = min(base + chunk, E);
  const int nvec = (end > base) ? ((end - base) >> 2) : 0;
  for (int v = threadIdx.x; v < nvec; v += 256) {
    const i32x4 d = __builtin_nontemporal_load((const i32x4*)(dst + base) + v);
    atomicAdd(&h[d[0] >> BINSHIFT], 1);
    atomicAdd(&h[d[1] >> BINSHIFT], 1);
    atomicAdd(&h[d[2] >> BINSHIFT], 1);
    atomicAdd(&h[d[3] >> BINSHIFT], 1);
  }
  for (int i = base + (nvec << 2) + threadIdx.x; i < end; i += 256)
    atomicAdd(&h[__builtin_nontemporal_load(dst + i) >> BINSHIFT], 1);
  __syncthreads();
  for (int i = threadIdx.x; i < nbins; i += 256)
    G[i * ABLK + blockIdx.x] = h[i];
}

// ---- pass A2a: per-bin local exclusive scan over ABLK=512 (2/thread) ----
__global__ __launch_bounds__(256) void scan_local_kernel(
    int* __restrict__ G, int* __restrict__ binTot) {
  __shared__ int sc[256];
  const int b = blockIdx.x;
  const int i0 = b * ABLK + 2 * threadIdx.x;
  const int v0 = G[i0];
  const int v1 = G[i0 + 1];
  const int s = v0 + v1;
  sc[threadIdx.x] = s;
  __syncthreads();
  for (int off = 1; off < 256; off <<= 1) {
    const int mine = sc[threadIdx.x];
    const int add = (threadIdx.x >= off) ? sc[threadIdx.x - off] : 0;
    __syncthreads();
    sc[threadIdx.x] = mine + add;
    __syncthreads();
  }
  const int base = sc[threadIdx.x] - s;  // exclusive
  G[i0] = base;
  G[i0 + 1] = base + v0;
  if (threadIdx.x == 255) binTot[b] = sc[255];
}

// ---- pass A2b: exclusive scan of bin totals (single block, <=512 bins) ----
__global__ __launch_bounds__(256) void scan_bins_kernel(
    const int* __restrict__ binTot, int* __restrict__ binBase, int nbins,
    int E) {
  __shared__ int sc[512];
  sc[threadIdx.x] = (threadIdx.x < nbins) ? binTot[threadIdx.x] : 0;
  sc[threadIdx.x + 256] =
      (threadIdx.x + 256 < nbins) ? binTot[threadIdx.x + 256] : 0;
  for (int d = 1; d < 512; d <<= 1) {
    __syncthreads();
    const int idx = (threadIdx.x + 1) * (d << 1) - 1;
    if (idx < 512) sc[idx] += sc[idx - d];
  }
  __syncthreads();
  if (threadIdx.x == 0) sc[511] = 0;
  for (int d = 256; d >= 1; d >>= 1) {
    __syncthreads();
    const int idx = (threadIdx.x + 1) * (d << 1) - 1;
    if (idx < 512) {
      const int tmp = sc[idx - d];
      sc[idx - d] = sc[idx];
      sc[idx] += tmp;
    }
  }
  __syncthreads();
  if (threadIdx.x < nbins) binBase[threadIdx.x] = sc[threadIdx.x];
  if (threadIdx.x + 256 < nbins) binBase[threadIdx.x + 256] = sc[threadIdx.x + 256];
  if (threadIdx.x == 0) binBase[nbins] = E;
}

// ---- pass A3: scatter edges into bin-grouped array (packed src|dstlow, w) ----
__global__ __launch_bounds__(256) void binscatter_kernel(
    const int* __restrict__ src, const int* __restrict__ dst,
    const float* __restrict__ ew, const int* __restrict__ G,
    const int* __restrict__ binBase, int2* __restrict__ bsw, int E, int nbins,
    int chunk) {
  __shared__ int cur[MAXBINS];
  for (int i = threadIdx.x; i < nbins; i += 256)
    cur[i] = binBase[i] + G[i * ABLK + blockIdx.x];
  __syncthreads();
  const int base = blockIdx.x * chunk;
  const int end = min(base + chunk, E);
  const int nvec = (end > base) ? ((end - base) >> 2) : 0;
  for (int v = threadIdx.x; v < nvec; v += 256) {
    const i32x4 d = __builtin_nontemporal_load((const i32x4*)(dst + base) + v);
    const i32x4 s = __builtin_nontemporal_load((const i32x4*)(src + base) + v);
    const fp32x4 w = __builtin_nontemporal_load((const fp32x4*)(ew + base) + v);
#pragma unroll
    for (int j = 0; j < 4; ++j) {
      const int p = atomicAdd(&cur[d[j] >> BINSHIFT], 1);
      bsw[p] = make_int2(s[j] | ((d[j] & 255) << SRCBITS),
                         __float_as_int(w[j]));
    }
  }
  for (int i = base + (nvec << 2) + threadIdx.x; i < end; i += 256) {
    const int d = __builtin_nontemporal_load(dst + i);
    const int s = __builtin_nontemporal_load(src + i);
    const float w = __builtin_nontemporal_load(ew + i);
    const int p = atomicAdd(&cur[d >> BINSHIFT], 1);
    bsw[p] = make_int2(s | ((d & 255) << SRCBITS), __float_as_int(w));
  }
}

// ---- pass B: per-bin rowptr + csr; bin slice staged in LDS; 8 waves ----
__global__ __launch_bounds__(512) void csrbuild_kernel(
    const long* __restrict__ bsw, const int* __restrict__ binBase,
    int* __restrict__ rowptr, int2* __restrict__ csr, int N, int E,
    int nbins) {
  constexpr int CAP = 6144;
  __shared__ long stage[CAP];
  __shared__ int deg[256];
  __shared__ int sc[256];
  const int tid = threadIdx.x;
  const int b = blockIdx.x;
  const int node0 = b << BINSHIFT;
  const int beg = binBase[b];
  const int cnt = binBase[b + 1] - beg;
  const bool fit = (cnt <= CAP);

  if (tid < 256) deg[tid] = 0;
  __syncthreads();
  for (int i = tid; i < cnt; i += 512) {
    const long c = __builtin_nontemporal_load(bsw + beg + i);
    if (fit) stage[i] = c;
    atomicAdd(&deg[((int)c >> SRCBITS) & 255], 1);
  }
  __syncthreads();

  int s = 0;
  if (tid < 256) { s = deg[tid]; sc[tid] = s; }
  __syncthreads();
  for (int off = 1; off < 256; off <<= 1) {
    int m = 0, add = 0;
    if (tid < 256) {
      m = sc[tid];
      add = (tid >= off) ? sc[tid - off] : 0;
    }
    __syncthreads();
    if (tid < 256) sc[tid] = m + add;
    __syncthreads();
  }
  if (tid < 256) {
    const int rp = beg + sc[tid] - s;  // exclusive
    if (node0 + tid < N) rowptr[node0 + tid] = rp;
    deg[tid] = rp;  // reuse as cursor
  }
  __syncthreads();
  for (int i = tid; i < cnt; i += 512) {
    const long c = fit ? stage[i] : bsw[beg + i];
    const int lo = (int)c;
    const int p = atomicAdd(&deg[(lo >> SRCBITS) & 255], 1);
    csr[p] = make_int2(lo & SRCMASK, (int)(c >> 32));
  }
  if (b == 0 && tid == 0) rowptr[N] = E;
}

// ---------------- W prep: fp32 [128][NC] -> bf16 WT[n][k] with XOR swizzle
__global__ __launch_bounds__(256) void prep_w_kernel(
    const float* __restrict__ W1, const float* __restrict__ W2,
    const float* __restrict__ W3, unsigned short* __restrict__ WT1,
    unsigned short* __restrict__ WT2, unsigned short* __restrict__ WT3) {
  const int id = blockIdx.x * 256 + threadIdx.x;
  const float* W;
  unsigned short* WT;
  int NC, idx;
  if (id < 16384) { W = W1; WT = WT1; NC = 128; idx = id; }
  else if (id < 32768) { W = W2; WT = WT2; NC = 128; idx = id - 16384; }
  else if (id < 40960) { W = W3; WT = WT3; NC = 64; idx = id - 32768; }
  else return;
  const int k = idx / NC, n = idx % NC;
  *(unsigned short*)((char*)WT + n * 256 + ((2 * k) ^ ((n & 7) << 4))) =
      f2bf(W[idx]);
}

// ---------------- bf16 MFMA GEMM: 512 thr, 128 rows/block ----------------
template <int NC, bool IN_F32>
__global__ __launch_bounds__(512) void gemm_mfma_kernel(
    const void* __restrict__ in, const unsigned short* __restrict__ WT,
    unsigned short* __restrict__ outp, int nrows) {
  constexpr int NT = NC / 16;
  __shared__ unsigned short Wlds[NC * 128];
  {
    const float4* wsrc = (const float4*)WT;
    float4* wdst = (float4*)Wlds;
    for (int i = threadIdx.x; i < NC * 256 / 16; i += 512) wdst[i] = wsrc[i];
  }
  __syncthreads();

  const int lane = threadIdx.x & 63;
  const int wave = threadIdx.x >> 6;   // 0..7
  const int nl = lane & 15;
  const int kl = (lane >> 4) * 8;
  const int rb = blockIdx.x * 128 + wave * 16;
  const int ra = min(rb + nl, nrows - 1);
  const int swz = (nl & 7) << 4;
  const char* wbase = (const char*)Wlds + nl * 256;

  f32x4 acc[NT] = {};

#pragma unroll
  for (int k0 = 0; k0 < 128; k0 += 32) {
    short8 a;
    if (IN_F32) {
      const float* xp = (const float*)in + (size_t)ra * 128 + k0 + kl;
      const float4 x0 = *(const float4*)xp;
      const float4 x1 = *(const float4*)(xp + 4);
      a[0] = (short)f2bf(x0.x); a[1] = (short)f2bf(x0.y);
      a[2] = (short)f2bf(x0.z); a[3] = (short)f2bf(x0.w);
      a[4] = (short)f2bf(x1.x); a[5] = (short)f2bf(x1.y);
      a[6] = (short)f2bf(x1.z); a[7] = (short)f2bf(x1.w);
    } else {
      a = *(const short8*)((const unsigned short*)in + (size_t)ra * 128 + k0 + kl);
    }
    const int koff = (2 * (k0 + kl)) ^ swz;
#pragma unroll
    for (int ct = 0; ct < NT; ++ct) {
      const short8 b = *(const short8*)(wbase + ct * 4096 + koff);
      acc[ct] = __builtin_amdgcn_mfma_f32_16x16x32_bf16(a, b, acc[ct], 0, 0, 0);
    }
  }

  const int r0 = rb + (lane >> 4) * 4;
#pragma unroll
  for (int ct = 0; ct < NT; ++ct) {
#pragma unroll
    for (int j = 0; j < 4; ++j) {
      const int r = r0 + j;
      if (r < nrows) outp[(size_t)r * NC + ct * 16 + nl] = f2bf(acc[ct][j]);
    }
  }
}

// ---------------- gather128: 1 node/wave, 8-edge unroll --------------------
template <bool BF16OUT>
__global__ __launch_bounds__(256) void gather128_kernel(
    const unsigned short* __restrict__ t, const long* __restrict__ csr,
    const int* __restrict__ rowptr, const float* __restrict__ bias,
    void* __restrict__ outp, int n) {
  const int lane = threadIdx.x & 63;
  const int node = blockIdx.x * 4 + (threadIdx.x >> 6);
  if (node >= n) return;
  const int beg = __builtin_amdgcn_readfirstlane(rowptr[node]);
  const int end = __builtin_amdgcn_readfirstlane(rowptr[node + 1]);

  float2 ac[8];
  ac[0] = *(const float2*)&bias[lane * 2];
#pragma unroll
  for (int j = 1; j < 8; ++j) ac[j] = {0.f, 0.f};

  int e = beg;
  for (; e + 8 <= end; e += 8) {
    long c[8];
#pragma unroll
    for (int j = 0; j < 8; ++j) c[j] = __builtin_nontemporal_load(csr + e + j);
    unsigned v[8];
#pragma unroll
    for (int j = 0; j < 8; ++j)
      v[j] = *(const unsigned*)&t[(size_t)(int)c[j] * 128 + lane * 2];
#pragma unroll
    for (int j = 0; j < 8; ++j) {
      const float w = __int_as_float((int)(c[j] >> 32));
      ac[j].x = fmaf(bf2f((unsigned short)v[j]), w, ac[j].x);
      ac[j].y = fmaf(bf2f((unsigned short)(v[j] >> 16)), w, ac[j].y);
    }
  }
  for (; e < end; ++e) {
    const long c = __builtin_nontemporal_load(csr + e);
    const unsigned v = *(const unsigned*)&t[(size_t)(int)c * 128 + lane * 2];
    const float w = __int_as_float((int)(c >> 32));
    ac[0].x = fmaf(bf2f((unsigned short)v), w, ac[0].x);
    ac[0].y = fmaf(bf2f((unsigned short)(v >> 16)), w, ac[0].y);
  }
#pragma unroll
  for (int j = 1; j < 8; ++j) {
    ac[0].x += ac[j].x;
    ac[0].y += ac[j].y;
  }
  if (BF16OUT) {
    ac[0].x = fmaxf(ac[0].x, 0.f);
    ac[0].y = fmaxf(ac[0].y, 0.f);
    const unsigned pk = (unsigned)f2bf(ac[0].x) | ((unsigned)f2bf(ac[0].y) << 16);
    *(unsigned*)((unsigned short*)outp + (size_t)node * 128 + lane * 2) = pk;
  } else {
    *(float2*)((float*)outp + (size_t)node * 128 + lane * 2) = ac[0];
  }
}

// ---------------- gather64: 4 nodes/wave, 8-edge unroll, fp32 out ---------
__global__ __launch_bounds__(256) void gather64_kernel(
    const unsigned short* __restrict__ t, const long* __restrict__ csr,
    const int* __restrict__ rowptr, const float* __restrict__ bias,
    float* __restrict__ outp, int n) {
  const int wave = threadIdx.x >> 6;
  const int q = (threadIdx.x >> 4) & 3;
  const int ql = threadIdx.x & 15;
  const int node = blockIdx.x * 16 + wave * 4 + q;
  if (node >= n) return;
  int e = rowptr[node];
  const int end = rowptr[node + 1];

  float4 ac[8];
  ac[0] = *(const float4*)&bias[ql * 4];
#pragma unroll
  for (int j = 1; j < 8; ++j) ac[j] = {0.f, 0.f, 0.f, 0.f};

  for (; e + 8 <= end; e += 8) {
    long c[8];
#pragma unroll
    for (int j = 0; j < 8; ++j) c[j] = __builtin_nontemporal_load(csr + e + j);
    uint2 v[8];
#pragma unroll
    for (int j = 0; j < 8; ++j)
      v[j] = *(const uint2*)&t[(size_t)(int)c[j] * 64 + ql * 4];
#pragma unroll
    for (int j = 0; j < 8; ++j) {
      const float w = __int_as_float((int)(c[j] >> 32));
      ac[j].x = fmaf(bf2f((unsigned short)v[j].x), w, ac[j].x);
      ac[j].y = fmaf(bf2f((unsigned short)(v[j].x >> 16)), w, ac[j].y);
      ac[j].z = fmaf(bf2f((unsigned short)v[j].y), w, ac[j].z);
      ac[j].w = fmaf(bf2f((unsigned short)(v[j].y >> 16)), w, ac[j].w);
    }
  }
  for (; e < end; ++e) {
    const long c = __builtin_nontemporal_load(csr + e);
    const uint2 v = *(const uint2*)&t[(size_t)(int)c * 64 + ql * 4];
    const float w = __int_as_float((int)(c >> 32));
    ac[0].x = fmaf(bf2f((unsigned short)v.x), w, ac[0].x);
    ac[0].y = fmaf(bf2f((unsigned short)(v.x >> 16)), w, ac[0].y);
    ac[0].z = fmaf(bf2f((unsigned short)v.y), w, ac[0].z);
    ac[0].w = fmaf(bf2f((unsigned short)(v.y >> 16)), w, ac[0].w);
  }
#pragma unroll
  for (int j = 1; j < 8; ++j) {
    ac[0].x += ac[j].x;
    ac[0].y += ac[j].y;
    ac[0].z += ac[j].z;
    ac[0].w += ac[j].w;
  }
  *(float4*)&outp[(size_t)node * 64 + ql * 4] = ac[0];
}

// ---------------------------------------------------------------------------
extern "C" void kernel_launch(void* const* d_in, const int* in_sizes, int n_in,
                              void* d_out, int out_size, void* d_ws, size_t ws_size,
                              hipStream_t stream) {
  const float* x  = (const float*)d_in[0];
  const int*   ei = (const int*)d_in[1];
  const float* ew = (const float*)d_in[2];
  const float* W1 = (const float*)d_in[3];
  const float* b1 = (const float*)d_in[4];
  const float* W2 = (const float*)d_in[5];
  const float* b2 = (const float*)d_in[6];
  const float* W3 = (const float*)d_in[7];
  const float* b3 = (const float*)d_in[8];

  const int E = in_sizes[2];
  const int N = in_sizes[0] / 128;
  const int* src = ei;
  const int* dst = ei + E;

  const int nbins = (N + 255) >> BINSHIFT;
  const int chunk = (((E + ABLK - 1) / ABLK) + 3) & ~3;  // multiple of 4

  // workspace layout
  unsigned short* WT1 = (unsigned short*)d_ws;        // 16384
  unsigned short* WT2 = WT1 + 16384;                  // 16384
  unsigned short* WT3 = WT2 + 16384;                  // 8192
  unsigned short* t = WT3 + 8192;                     // N*128 bf16
  unsigned short* g = t + (size_t)N * 128;            // N*128 bf16
  int2* csr = (int2*)(g + (size_t)N * 128);           // E
  int* rowptr = (int*)(csr + E);                      // N+1
  int* G = rowptr + (N + 1);                          // nbins*ABLK
  int* binTot = G + nbins * ABLK;                     // nbins
  int* binBase = binTot + nbins;                      // nbins+1
  // bin-grouped temporary aliases the 'g' buffer (dead until gather1 writes)
  int2* bsw = (int2*)g;                               // E

  const int gemm_blocks = (N + 127) / 128;
  const int g128_blocks = (N + 3) / 4;
  const int g64_blocks = (N + 15) / 16;

  // ---- W prep + CSR build ----
  prep_w_kernel<<<160, 256, 0, stream>>>(W1, W2, W3, WT1, WT2, WT3);
  binhist_kernel<<<ABLK, 256, 0, stream>>>(dst, G, E, nbins, chunk);
  scan_local_kernel<<<nbins, 256, 0, stream>>>(G, binTot);
  scan_bins_kernel<<<1, 256, 0, stream>>>(binTot, binBase, nbins, E);
  binscatter_kernel<<<ABLK, 256, 0, stream>>>(src, dst, ew, G, binBase, bsw,
                                              E, nbins, chunk);
  csrbuild_kernel<<<nbins, 512, 0, stream>>>((const long*)bsw, binBase,
                                             rowptr, csr, N, E, nbins);

  // ---- layer 1 ----
  gemm_mfma_kernel<128, true><<<gemm_blocks, 512, 0, stream>>>(x, WT1, t, N);
  gather128_kernel<true><<<g128_blocks, 256, 0, stream>>>(
      t, (const long*)csr, rowptr, b1, g, N);

  // ---- layer 2 ----
  gemm_mfma_kernel<128, false><<<gemm_blocks, 512, 0, stream>>>(g, WT2, t, N);
  gather128_kernel<true><<<g128_blocks, 256, 0, stream>>>(
      t, (const long*)csr, rowptr, b2, g, N);

  // ---- layer 3 ----
  gemm_mfma_kernel<64, false><<<gemm_blocks, 512, 0, stream>>>(g, WT3, t, N);
  gather64_kernel<<<g64_blocks, 256, 0, stream>>>(
      t, (const long*)csr, rowptr, b3, (float*)d_out, N);
}

// Round 12
// 263.216 us; speedup vs baseline: 1.0267x; 1.0267x over previous
//
#include <hip/hip_runtime.h>

// ---------------------------------------------------------------------------
// GCN 3-layer forward. Round 12: revert to the measured-best R10 config
// (R11's csrbuild-512 / gemm-512x128 / gather64-unroll8 netted -6.7us).
//   - binned counting-sort CSR build (no global atomics, merged writes)
//   - bf16 MFMA GEMMs, W pre-transposed+XOR-swizzled in ws
//   - bf16 intermediate features; bias/relu fused into gathers
//   - gather128: 1 node/wave, 8-edge unroll (L3-random-row-BW-bound,
//     ~59.5us each vs ~51us structural floor: 8 non-coherent L2s x 25.6MB
//     table => ~190-205MB L3 fetch @ ~3.6TB/s random-256B ceiling)
// ---------------------------------------------------------------------------

typedef __attribute__((ext_vector_type(8))) short short8;
typedef __attribute__((ext_vector_type(4))) float f32x4;
typedef __attribute__((ext_vector_type(4))) int i32x4;
typedef __attribute__((ext_vector_type(4))) float fp32x4;

__device__ __forceinline__ unsigned short f2bf(float f) {
  union { float f; unsigned u; } v; v.f = f;
  unsigned r = v.u + 0x7fffu + ((v.u >> 16) & 1u);  // RNE
  return (unsigned short)(r >> 16);
}
__device__ __forceinline__ float bf2f(unsigned short h) {
  union { unsigned u; float f; } v; v.u = (unsigned)h << 16;
  return v.f;
}

constexpr int ABLK = 512;      // blocks in binning passes (2 blocks/CU)
constexpr int BINSHIFT = 8;    // 256 nodes per bin
constexpr int MAXBINS = 512;
constexpr int SRCBITS = 17;    // N < 131072
constexpr int SRCMASK = (1 << SRCBITS) - 1;

// ---- pass A1: G[bin*ABLK + blk] = count of this block's edges in bin ----
__global__ __launch_bounds__(256) void binhist_kernel(
    const int* __restrict__ dst, int* __restrict__ G, int E, int nbins,
    int chunk) {
  __shared__ int h[MAXBINS];
  for (int i = threadIdx.x; i < nbins; i += 256) h[i] = 0;
  __syncthreads();
  const int base = blockIdx.x * chunk;
  const int end = min(base + chunk, E);
  const int nvec = (end > base) ? ((end - base) >> 2) : 0;
  for (int v = threadIdx.x; v < nvec; v += 256) {
    const i32x4 d = __builtin_nontemporal_load((const i32x4*)(dst + base) + v);
    atomicAdd(&h[d[0] >> BINSHIFT], 1);
    atomicAdd(&h[d[1] >> BINSHIFT], 1);
    atomicAdd(&h[d[2] >> BINSHIFT], 1);
    atomicAdd(&h[d[3] >> BINSHIFT], 1);
  }
  for (int i = base + (nvec << 2) + threadIdx.x; i < end; i += 256)
    atomicAdd(&h[__builtin_nontemporal_load(dst + i) >> BINSHIFT], 1);
  __syncthreads();
  for (int i = threadIdx.x; i < nbins; i += 256)
    G[i * ABLK + blockIdx.x] = h[i];
}

// ---- pass A2a: per-bin local exclusive scan over ABLK=512 (2/thread) ----
__global__ __launch_bounds__(256) void scan_local_kernel(
    int* __restrict__ G, int* __restrict__ binTot) {
  __shared__ int sc[256];
  const int b = blockIdx.x;
  const int i0 = b * ABLK + 2 * threadIdx.x;
  const int v0 = G[i0];
  const int v1 = G[i0 + 1];
  const int s = v0 + v1;
  sc[threadIdx.x] = s;
  __syncthreads();
  for (int off = 1; off < 256; off <<= 1) {
    const int mine = sc[threadIdx.x];
    const int add = (threadIdx.x >= off) ? sc[threadIdx.x - off] : 0;
    __syncthreads();
    sc[threadIdx.x] = mine + add;
    __syncthreads();
  }
  const int base = sc[threadIdx.x] - s;  // exclusive
  G[i0] = base;
  G[i0 + 1] = base + v0;
  if (threadIdx.x == 255) binTot[b] = sc[255];
}

// ---- pass A2b: exclusive scan of bin totals (single block, <=512 bins) ----
__global__ __launch_bounds__(256) void scan_bins_kernel(
    const int* __restrict__ binTot, int* __restrict__ binBase, int nbins,
    int E) {
  __shared__ int sc[512];
  sc[threadIdx.x] = (threadIdx.x < nbins) ? binTot[threadIdx.x] : 0;
  sc[threadIdx.x + 256] =
      (threadIdx.x + 256 < nbins) ? binTot[threadIdx.x + 256] : 0;
  for (int d = 1; d < 512; d <<= 1) {
    __syncthreads();
    const int idx = (threadIdx.x + 1) * (d << 1) - 1;
    if (idx < 512) sc[idx] += sc[idx - d];
  }
  __syncthreads();
  if (threadIdx.x == 0) sc[511] = 0;
  for (int d = 256; d >= 1; d >>= 1) {
    __syncthreads();
    const int idx = (threadIdx.x + 1) * (d << 1) - 1;
    if (idx < 512) {
      const int tmp = sc[idx - d];
      sc[idx - d] = sc[idx];
      sc[idx] += tmp;
    }
  }
  __syncthreads();
  if (threadIdx.x < nbins) binBase[threadIdx.x] = sc[threadIdx.x];
  if (threadIdx.x + 256 < nbins) binBase[threadIdx.x + 256] = sc[threadIdx.x + 256];
  if (threadIdx.x == 0) binBase[nbins] = E;
}

// ---- pass A3: scatter edges into bin-grouped array (packed src|dstlow, w) ----
__global__ __launch_bounds__(256) void binscatter_kernel(
    const int* __restrict__ src, const int* __restrict__ dst,
    const float* __restrict__ ew, const int* __restrict__ G,
    const int* __restrict__ binBase, int2* __restrict__ bsw, int E, int nbins,
    int chunk) {
  __shared__ int cur[MAXBINS];
  for (int i = threadIdx.x; i < nbins; i += 256)
    cur[i] = binBase[i] + G[i * ABLK + blockIdx.x];
  __syncthreads();
  const int base = blockIdx.x * chunk;
  const int end = min(base + chunk, E);
  const int nvec = (end > base) ? ((end - base) >> 2) : 0;
  for (int v = threadIdx.x; v < nvec; v += 256) {
    const i32x4 d = __builtin_nontemporal_load((const i32x4*)(dst + base) + v);
    const i32x4 s = __builtin_nontemporal_load((const i32x4*)(src + base) + v);
    const fp32x4 w = __builtin_nontemporal_load((const fp32x4*)(ew + base) + v);
#pragma unroll
    for (int j = 0; j < 4; ++j) {
      const int p = atomicAdd(&cur[d[j] >> BINSHIFT], 1);
      bsw[p] = make_int2(s[j] | ((d[j] & 255) << SRCBITS),
                         __float_as_int(w[j]));
    }
  }
  for (int i = base + (nvec << 2) + threadIdx.x; i < end; i += 256) {
    const int d = __builtin_nontemporal_load(dst + i);
    const int s = __builtin_nontemporal_load(src + i);
    const float w = __builtin_nontemporal_load(ew + i);
    const int p = atomicAdd(&cur[d >> BINSHIFT], 1);
    bsw[p] = make_int2(s | ((d & 255) << SRCBITS), __float_as_int(w));
  }
}

// ---- pass B: per-bin rowptr + csr; bin slice staged in LDS ----
__global__ __launch_bounds__(256) void csrbuild_kernel(
    const long* __restrict__ bsw, const int* __restrict__ binBase,
    int* __restrict__ rowptr, int2* __restrict__ csr, int N, int E,
    int nbins) {
  constexpr int CAP = 6144;
  __shared__ long stage[CAP];
  __shared__ int deg[256];
  __shared__ int sc[256];
  const int b = blockIdx.x;
  const int node0 = b << BINSHIFT;
  const int beg = binBase[b];
  const int cnt = binBase[b + 1] - beg;
  const bool fit = (cnt <= CAP);

  deg[threadIdx.x] = 0;
  __syncthreads();
  for (int i = threadIdx.x; i < cnt; i += 256) {
    const long c = __builtin_nontemporal_load(bsw + beg + i);
    if (fit) stage[i] = c;
    atomicAdd(&deg[((int)c >> SRCBITS) & 255], 1);
  }
  __syncthreads();

  const int s = deg[threadIdx.x];
  sc[threadIdx.x] = s;
  __syncthreads();
  for (int off = 1; off < 256; off <<= 1) {
    const int mine = sc[threadIdx.x];
    const int add = (threadIdx.x >= off) ? sc[threadIdx.x - off] : 0;
    __syncthreads();
    sc[threadIdx.x] = mine + add;
    __syncthreads();
  }
  const int rp = beg + sc[threadIdx.x] - s;  // exclusive
  if (node0 + threadIdx.x < N) rowptr[node0 + threadIdx.x] = rp;
  deg[threadIdx.x] = rp;  // reuse as cursor
  __syncthreads();
  for (int i = threadIdx.x; i < cnt; i += 256) {
    const long c = fit ? stage[i] : bsw[beg + i];
    const int lo = (int)c;
    const int p = atomicAdd(&deg[(lo >> SRCBITS) & 255], 1);
    csr[p] = make_int2(lo & SRCMASK, (int)(c >> 32));
  }
  if (b == 0 && threadIdx.x == 0) rowptr[N] = E;
}

// ---------------- W prep: fp32 [128][NC] -> bf16 WT[n][k] with XOR swizzle
__global__ __launch_bounds__(256) void prep_w_kernel(
    const float* __restrict__ W1, const float* __restrict__ W2,
    const float* __restrict__ W3, unsigned short* __restrict__ WT1,
    unsigned short* __restrict__ WT2, unsigned short* __restrict__ WT3) {
  const int id = blockIdx.x * 256 + threadIdx.x;
  const float* W;
  unsigned short* WT;
  int NC, idx;
  if (id < 16384) { W = W1; WT = WT1; NC = 128; idx = id; }
  else if (id < 32768) { W = W2; WT = WT2; NC = 128; idx = id - 16384; }
  else if (id < 40960) { W = W3; WT = WT3; NC = 64; idx = id - 32768; }
  else return;
  const int k = idx / NC, n = idx % NC;
  *(unsigned short*)((char*)WT + n * 256 + ((2 * k) ^ ((n & 7) << 4))) =
      f2bf(W[idx]);
}

// ---------------- bf16 MFMA GEMM ----------------
template <int NC, bool IN_F32>
__global__ __launch_bounds__(256) void gemm_mfma_kernel(
    const void* __restrict__ in, const unsigned short* __restrict__ WT,
    unsigned short* __restrict__ outp, int nrows) {
  constexpr int NT = NC / 16;
  __shared__ unsigned short Wlds[NC * 128];
  {
    const float4* wsrc = (const float4*)WT;
    float4* wdst = (float4*)Wlds;
    for (int i = threadIdx.x; i < NC * 256 / 16; i += 256) wdst[i] = wsrc[i];
  }
  __syncthreads();

  const int lane = threadIdx.x & 63;
  const int wave = threadIdx.x >> 6;
  const int nl = lane & 15;
  const int kl = (lane >> 4) * 8;
  const int rb = blockIdx.x * 64 + wave * 16;
  const int ra = min(rb + nl, nrows - 1);
  const int swz = (nl & 7) << 4;
  const char* wbase = (const char*)Wlds + nl * 256;

  f32x4 acc[NT] = {};

#pragma unroll
  for (int k0 = 0; k0 < 128; k0 += 32) {
    short8 a;
    if (IN_F32) {
      const float* xp = (const float*)in + (size_t)ra * 128 + k0 + kl;
      const float4 x0 = *(const float4*)xp;
      const float4 x1 = *(const float4*)(xp + 4);
      a[0] = (short)f2bf(x0.x); a[1] = (short)f2bf(x0.y);
      a[2] = (short)f2bf(x0.z); a[3] = (short)f2bf(x0.w);
      a[4] = (short)f2bf(x1.x); a[5] = (short)f2bf(x1.y);
      a[6] = (short)f2bf(x1.z); a[7] = (short)f2bf(x1.w);
    } else {
      a = *(const short8*)((const unsigned short*)in + (size_t)ra * 128 + k0 + kl);
    }
    const int koff = (2 * (k0 + kl)) ^ swz;
#pragma unroll
    for (int ct = 0; ct < NT; ++ct) {
      const short8 b = *(const short8*)(wbase + ct * 4096 + koff);
      acc[ct] = __builtin_amdgcn_mfma_f32_16x16x32_bf16(a, b, acc[ct], 0, 0, 0);
    }
  }

  const int r0 = rb + (lane >> 4) * 4;
#pragma unroll
  for (int ct = 0; ct < NT; ++ct) {
#pragma unroll
    for (int j = 0; j < 4; ++j) {
      const int r = r0 + j;
      if (r < nrows) outp[(size_t)r * NC + ct * 16 + nl] = f2bf(acc[ct][j]);
    }
  }
}

// ---------------- gather128: 1 node/wave, 8-edge unroll --------------------
template <bool BF16OUT>
__global__ __launch_bounds__(256) void gather128_kernel(
    const unsigned short* __restrict__ t, const long* __restrict__ csr,
    const int* __restrict__ rowptr, const float* __restrict__ bias,
    void* __restrict__ outp, int n) {
  const int lane = threadIdx.x & 63;
  const int node = blockIdx.x * 4 + (threadIdx.x >> 6);
  if (node >= n) return;
  const int beg = __builtin_amdgcn_readfirstlane(rowptr[node]);
  const int end = __builtin_amdgcn_readfirstlane(rowptr[node + 1]);

  float2 ac[8];
  ac[0] = *(const float2*)&bias[lane * 2];
#pragma unroll
  for (int j = 1; j < 8; ++j) ac[j] = {0.f, 0.f};

  int e = beg;
  for (; e + 8 <= end; e += 8) {
    long c[8];
#pragma unroll
    for (int j = 0; j < 8; ++j) c[j] = __builtin_nontemporal_load(csr + e + j);
    unsigned v[8];
#pragma unroll
    for (int j = 0; j < 8; ++j)
      v[j] = *(const unsigned*)&t[(size_t)(int)c[j] * 128 + lane * 2];
#pragma unroll
    for (int j = 0; j < 8; ++j) {
      const float w = __int_as_float((int)(c[j] >> 32));
      ac[j].x = fmaf(bf2f((unsigned short)v[j]), w, ac[j].x);
      ac[j].y = fmaf(bf2f((unsigned short)(v[j] >> 16)), w, ac[j].y);
    }
  }
  for (; e < end; ++e) {
    const long c = __builtin_nontemporal_load(csr + e);
    const unsigned v = *(const unsigned*)&t[(size_t)(int)c * 128 + lane * 2];
    const float w = __int_as_float((int)(c >> 32));
    ac[0].x = fmaf(bf2f((unsigned short)v), w, ac[0].x);
    ac[0].y = fmaf(bf2f((unsigned short)(v >> 16)), w, ac[0].y);
  }
#pragma unroll
  for (int j = 1; j < 8; ++j) {
    ac[0].x += ac[j].x;
    ac[0].y += ac[j].y;
  }
  if (BF16OUT) {
    ac[0].x = fmaxf(ac[0].x, 0.f);
    ac[0].y = fmaxf(ac[0].y, 0.f);
    const unsigned pk = (unsigned)f2bf(ac[0].x) | ((unsigned)f2bf(ac[0].y) << 16);
    *(unsigned*)((unsigned short*)outp + (size_t)node * 128 + lane * 2) = pk;
  } else {
    *(float2*)((float*)outp + (size_t)node * 128 + lane * 2) = ac[0];
  }
}

// ---------------- gather64: 4 nodes/wave, fp32 out -----------------------
__device__ __forceinline__ void acc_edge64(const unsigned short* t, long c,
                                           int ql, float4& a) {
  const int s = (int)c;
  const float w = __int_as_float((int)(c >> 32));
  const uint2 v = *(const uint2*)&t[(size_t)s * 64 + ql * 4];
  a.x = fmaf(bf2f((unsigned short)v.x), w, a.x);
  a.y = fmaf(bf2f((unsigned short)(v.x >> 16)), w, a.y);
  a.z = fmaf(bf2f((unsigned short)v.y), w, a.z);
  a.w = fmaf(bf2f((unsigned short)(v.y >> 16)), w, a.w);
}

__global__ __launch_bounds__(256) void gather64_kernel(
    const unsigned short* __restrict__ t, const long* __restrict__ csr,
    const int* __restrict__ rowptr, const float* __restrict__ bias,
    float* __restrict__ outp, int n) {
  const int wave = threadIdx.x >> 6;
  const int q = (threadIdx.x >> 4) & 3;
  const int ql = threadIdx.x & 15;
  const int node = blockIdx.x * 16 + wave * 4 + q;
  if (node >= n) return;
  int e = rowptr[node];
  const int end = rowptr[node + 1];

  float4 a0 = *(const float4*)&bias[ql * 4];
  float4 a1 = {0, 0, 0, 0}, a2 = {0, 0, 0, 0}, a3 = {0, 0, 0, 0};
  for (; e + 4 <= end; e += 4) {
    const long c0 = __builtin_nontemporal_load(csr + e);
    const long c1 = __builtin_nontemporal_load(csr + e + 1);
    const long c2 = __builtin_nontemporal_load(csr + e + 2);
    const long c3 = __builtin_nontemporal_load(csr + e + 3);
    acc_edge64(t, c0, ql, a0);
    acc_edge64(t, c1, ql, a1);
    acc_edge64(t, c2, ql, a2);
    acc_edge64(t, c3, ql, a3);
  }
  for (; e < end; ++e)
    acc_edge64(t, __builtin_nontemporal_load(csr + e), ql, a0);
  a0.x += a1.x + a2.x + a3.x;
  a0.y += a1.y + a2.y + a3.y;
  a0.z += a1.z + a2.z + a3.z;
  a0.w += a1.w + a2.w + a3.w;
  *(float4*)&outp[(size_t)node * 64 + ql * 4] = a0;
}

// ---------------------------------------------------------------------------
extern "C" void kernel_launch(void* const* d_in, const int* in_sizes, int n_in,
                              void* d_out, int out_size, void* d_ws, size_t ws_size,
                              hipStream_t stream) {
  const float* x  = (const float*)d_in[0];
  const int*   ei = (const int*)d_in[1];
  const float* ew = (const float*)d_in[2];
  const float* W1 = (const float*)d_in[3];
  const float* b1 = (const float*)d_in[4];
  const float* W2 = (const float*)d_in[5];
  const float* b2 = (const float*)d_in[6];
  const float* W3 = (const float*)d_in[7];
  const float* b3 = (const float*)d_in[8];

  const int E = in_sizes[2];
  const int N = in_sizes[0] / 128;
  const int* src = ei;
  const int* dst = ei + E;

  const int nbins = (N + 255) >> BINSHIFT;
  const int chunk = (((E + ABLK - 1) / ABLK) + 3) & ~3;  // multiple of 4

  // workspace layout
  unsigned short* WT1 = (unsigned short*)d_ws;        // 16384
  unsigned short* WT2 = WT1 + 16384;                  // 16384
  unsigned short* WT3 = WT2 + 16384;                  // 8192
  unsigned short* t = WT3 + 8192;                     // N*128 bf16
  unsigned short* g = t + (size_t)N * 128;            // N*128 bf16
  int2* csr = (int2*)(g + (size_t)N * 128);           // E
  int* rowptr = (int*)(csr + E);                      // N+1
  int* G = rowptr + (N + 1);                          // nbins*ABLK
  int* binTot = G + nbins * ABLK;                     // nbins
  int* binBase = binTot + nbins;                      // nbins+1
  // bin-grouped temporary aliases the 'g' buffer (dead until gather1 writes)
  int2* bsw = (int2*)g;                               // E

  const int gemm_blocks = (N + 63) / 64;
  const int g128_blocks = (N + 3) / 4;
  const int g64_blocks = (N + 15) / 16;

  // ---- W prep + CSR build ----
  prep_w_kernel<<<160, 256, 0, stream>>>(W1, W2, W3, WT1, WT2, WT3);
  binhist_kernel<<<ABLK, 256, 0, stream>>>(dst, G, E, nbins, chunk);
  scan_local_kernel<<<nbins, 256, 0, stream>>>(G, binTot);
  scan_bins_kernel<<<1, 256, 0, stream>>>(binTot, binBase, nbins, E);
  binscatter_kernel<<<ABLK, 256, 0, stream>>>(src, dst, ew, G, binBase, bsw,
                                              E, nbins, chunk);
  csrbuild_kernel<<<nbins, 256, 0, stream>>>((const long*)bsw, binBase,
                                             rowptr, csr, N, E, nbins);

  // ---- layer 1 ----
  gemm_mfma_kernel<128, true><<<gemm_blocks, 256, 0, stream>>>(x, WT1, t, N);
  gather128_kernel<true><<<g128_blocks, 256, 0, stream>>>(
      t, (const long*)csr, rowptr, b1, g, N);

  // ---- layer 2 ----
  gemm_mfma_kernel<128, false><<<gemm_blocks, 256, 0, stream>>>(g, WT2, t, N);
  gather128_kernel<true><<<g128_blocks, 256, 0, stream>>>(
      t, (const long*)csr, rowptr, b2, g, N);

  // ---- layer 3 ----
  gemm_mfma_kernel<64, false><<<gemm_blocks, 256, 0, stream>>>(g, WT3, t, N);
  gather64_kernel<<<g64_blocks, 256, 0, stream>>>(
      t, (const long*)csr, rowptr, b3, (float*)d_out, N);
}